// Round 8
// baseline (53.723 us; speedup 1.0000x reference)
//
#include <hip/hip_runtime.h>

#define STEP 10
#define NCH  256                 // 128*2 flattened channels = DP "batches"
#define CSCL (-144.2695041f)     // -(1/GAMMA)*log2(e): scale into log2 domain
#define GLN2 (-0.00693147181f)   // -GAMMA*ln(2) == 1/CSCL (to 7e-10 rel)
#define BIGP (-1.442695041e12f)  // 1e10 * CSCL : boundary "BIG" in scaled domain
#define YOFF 64                  // pad: y idx = s-64w-l-2 >= -63
#define YLDS 384                 // YOFF + N + 80 for N <= 240
#define BNDSZ 472                // absolute-diag-indexed boundary ring (no reuse)
#define NW   4                   // waves per batch

// exp2/log2 via raw ISA (no fast-math dependence)
__device__ __forceinline__ float fexp2(float x){ float r; asm("v_exp_f32 %0, %1" : "=v"(r) : "v"(x)); return r; }
__device__ __forceinline__ float flog2(float x){ float r; asm("v_log_f32 %0, %1" : "=v"(r) : "v"(x)); return r; }

// Fused whole-wave shift + lane-0 boundary inject: lane i <- lane i-1's src,
// lane 0 <- old (bound_ctrl=false keeps OLD where the shift has no source).
// Exactly equivalent to (l==0) ? h : shfl_up(src,1) — one chain level shorter
// than dpp + cndmask.
__device__ __forceinline__ float dpp_shr1_sel(float h, float src){
    int o = __builtin_bit_cast(int, h);
    int s = __builtin_bit_cast(int, src);
    int r = __builtin_amdgcn_update_dpp(o, s, 0x138 /*wave_shr:1*/, 0xF, 0xF, false);
    return __builtin_bit_cast(float, r);
}

// Soft-DTW cell, scaled domain R' = R*CSCL, qq = (x-y)^2*CSCL precomputed.
// No boundary mask: invalid cells self-perpetuate at ~BIGP and contribute
// exactly 0.0f through exp2 in any valid cell (validated R4-R7, absmax 0.0).
__device__ __forceinline__ float dpcell(float up2, float up, float left, float qq) {
    float m  = fmaxf(fmaxf(up2, up), left);            // v_max3_f32
    float lo = fminf(fminf(up2, up), left);            // v_min3_f32
    float md = __builtin_amdgcn_fmed3f(up2, up, left); // v_med3_f32
    float e  = fexp2(lo - m) + fexp2(md - m) + 1.0f;
    float mq = m + qq;                                 // off-chain
    return flog2(e) + mq;
}

// R7's barrier-free 4-wave lag pipeline (1 row/lane, software-pipelined group
// prefetch, trimmed spans, launch_bounds(256,1)), now advancing TWO independent
// batches per block: the second batch's ~35 cy/step of issue fills the first
// batch's chain-stall cycles (in-order issue, 1 wave/SIMD — stalls are
// otherwise pure idle). One shared progress counter per wave pair (both
// batches publish together): one poll, one acquire per group.
__global__ __launch_bounds__(256, 1)
void softdtw_wave(const float* __restrict__ x, const float* __restrict__ y,
                  float* __restrict__ ws, int N) {
    const int bA = blockIdx.x * 2;
    const int bB = bA + 1;
    const int t = threadIdx.x;          // 0..255
    const int l = t & 63;               // lane within wave
    const int w = t >> 6;               // wave 0..3

    __shared__ __align__(16) float YsA[YLDS], YsB[YLDS];
    __shared__ float bndA[NW - 1][BNDSZ], bndB[NW - 1][BNDSZ];
    __shared__ int prog[NW - 1];

    for (int j = t; j < YLDS; j += 256) { YsA[j] = 0.f; YsB[j] = 0.f; }
    float* bfA = &bndA[0][0]; float* bfB = &bndB[0][0];
    for (int j = t; j < (NW - 1) * BNDSZ; j += 256) { bfA[j] = BIGP; bfB[j] = BIGP; }
    if (t < NW - 1) prog[t] = 0;
    __syncthreads();
    for (int j = t; j < N; j += 256) {
        YsA[YOFF + j] = y[j * STEP * NCH + bA];
        YsB[YOFF + j] = y[j * STEP * NCH + bB];
    }
    __syncthreads();                    // the only block-wide barriers (startup)

    const int i = 64 * w + l + 1;       // my row (same row for both batches)
    const float xvA = (i <= N) ? x[(i - 1) * STEP * NCH + bA] : 0.f;
    const float xvB = (i <= N) ? x[(i - 1) * STEP * NCH + bB] : 0.f;

    // scaled DP state entering diag s (per batch):
    //   sp = R'(i, s-1-i)   bp = R'(i-1, s-i)   bq = R'(i-1, s-1-i)
    float spA = BIGP, bpA = BIGP, bqA = (t == 0) ? 0.0f : BIGP;
    float spB = BIGP, bpB = BIGP, bqB = (t == 0) ? 0.0f : BIGP;

    const int smax = 2 * N;
    const int sb0  = 64 * w + 2;        // first diagonal of this wave
    // trimmed group count: last diag this wave needs = min(64(w+1), N) + N
    const int myrows = (64 * (w + 1) < N) ? 64 * (w + 1) : N;
    const int NG     = (myrows + N - sb0 + 1 + 7) >> 3;
    const bool prod = (w < NW - 1);
    const bool cons = (w > 0);
    // producer (w-1)'s trimmed final publish
    const int prows = (64 * w < N) ? 64 * w : N;
    const int pNG   = (prows + N - (sb0 - 64) + 1 + 7) >> 3;
    const int progFinal = (sb0 - 64) + 8 * pNG - 1;

    // per-lane y pointers: group m, step J reads yb[8m+J] = Ys[YOFF + sb+J-i-1]
    const float* ybA = YsA + (YOFF - l);
    const float* ybB = YsB + (YOFF - l);
    const float* bbA = cons ? bndA[w - 1] : bndA[0];
    const float* bbB = cons ? bndB[w - 1] : bndB[0];

    #define POLL(NEED) do {                                               \
        const int need_ = min((NEED), progFinal);                         \
        while (__hip_atomic_load(&prog[w - 1], __ATOMIC_ACQUIRE,          \
                                 __HIP_MEMORY_SCOPE_WORKGROUP) < need_)   \
            __builtin_amdgcn_s_sleep(1);                                  \
    } while (0)

    // ---- prologue: prefetch group 0 for both batches ----
    float qA0,qA1,qA2,qA3,qA4,qA5,qA6,qA7, qB0,qB1,qB2,qB3,qB4,qB5,qB6,qB7;
    float hA0,hA1,hA2,hA3,hA4,hA5,hA6,hA7, hB0,hB1,hB2,hB3,hB4,hB5,hB6,hB7;
    {
        float a0=ybA[0],a1=ybA[1],a2=ybA[2],a3=ybA[3];
        float a4=ybA[4],a5=ybA[5],a6=ybA[6],a7=ybA[7];
        float e0=ybB[0],e1=ybB[1],e2=ybB[2],e3=ybB[3];
        float e4=ybB[4],e5=ybB[5],e6=ybB[6],e7=ybB[7];
        if (cons) {
            POLL(sb0 + 7);
            if (l == 0) { bpA = bbA[sb0 - 1]; bpB = bbB[sb0 - 1]; }  // seed R'(64w,1)
            hA0=bbA[sb0+0]; hA1=bbA[sb0+1]; hA2=bbA[sb0+2]; hA3=bbA[sb0+3];
            hA4=bbA[sb0+4]; hA5=bbA[sb0+5]; hA6=bbA[sb0+6]; hA7=bbA[sb0+7];
            hB0=bbB[sb0+0]; hB1=bbB[sb0+1]; hB2=bbB[sb0+2]; hB3=bbB[sb0+3];
            hB4=bbB[sb0+4]; hB5=bbB[sb0+5]; hB6=bbB[sb0+6]; hB7=bbB[sb0+7];
        } else {
            hA0=hA1=hA2=hA3=hA4=hA5=hA6=hA7 = BIGP;    // row-0 wall (constant)
            hB0=hB1=hB2=hB3=hB4=hB5=hB6=hB7 = BIGP;
        }
        float d;
        d=xvA-a0; qA0=d*CSCL*d;  d=xvA-a1; qA1=d*CSCL*d;
        d=xvA-a2; qA2=d*CSCL*d;  d=xvA-a3; qA3=d*CSCL*d;
        d=xvA-a4; qA4=d*CSCL*d;  d=xvA-a5; qA5=d*CSCL*d;
        d=xvA-a6; qA6=d*CSCL*d;  d=xvA-a7; qA7=d*CSCL*d;
        d=xvB-e0; qB0=d*CSCL*d;  d=xvB-e1; qB1=d*CSCL*d;
        d=xvB-e2; qB2=d*CSCL*d;  d=xvB-e3; qB3=d*CSCL*d;
        d=xvB-e4; qB4=d*CSCL*d;  d=xvB-e5; qB5=d*CSCL*d;
        d=xvB-e6; qB6=d*CSCL*d;  d=xvB-e7; qB7=d*CSCL*d;
    }

    #define STEPJ2(QA, HA, CA, QB, HB, CB, J) do {                 \
        CA = dpcell(bqA, bpA, spA, (QA));                          \
        CB = dpcell(bqB, bpB, spB, (QB));                          \
        float nA = dpp_shr1_sel((HA), CA);                         \
        float nB = dpp_shr1_sel((HB), CB);                         \
        bqA = bpA; bpA = nA; spA = CA;                             \
        bqB = bpB; bpB = nB; spB = CB;                             \
        if (sb + (J) == smax && i == N) {                          \
            ws[bA] = CA * GLN2; ws[bB] = CB * GLN2;                \
        }                                                          \
    } while (0)

    for (int m = 0; m < NG; ++m) {
        const int sb = sb0 + 8 * m;
        float cA0,cA1,cA2,cA3,cA4,cA5,cA6,cA7;
        float cB0,cB1,cB2,cB3,cB4,cB5,cB6,cB7;
        STEPJ2(qA0,hA0,cA0, qB0,hB0,cB0, 0);
        STEPJ2(qA1,hA1,cA1, qB1,hB1,cB1, 1);
        STEPJ2(qA2,hA2,cA2, qB2,hB2,cB2, 2);
        STEPJ2(qA3,hA3,cA3, qB3,hB3,cB3, 3);
        STEPJ2(qA4,hA4,cA4, qB4,hB4,cB4, 4);
        STEPJ2(qA5,hA5,cA5, qB5,hB5,cB5, 5);
        STEPJ2(qA6,hA6,cA6, qB6,hB6,cB6, 6);
        STEPJ2(qA7,hA7,cA7, qB7,hB7,cB7, 7);

        // batched boundary publish: one exec-mask toggle, 16 writes, 1 release
        if (prod && l == 63) {
            float* bwA = &bndA[w][sb];
            bwA[0]=cA0; bwA[1]=cA1; bwA[2]=cA2; bwA[3]=cA3;
            bwA[4]=cA4; bwA[5]=cA5; bwA[6]=cA6; bwA[7]=cA7;
            float* bwB = &bndB[w][sb];
            bwB[0]=cB0; bwB[1]=cB1; bwB[2]=cB2; bwB[3]=cB3;
            bwB[4]=cB4; bwB[5]=cB5; bwB[6]=cB6; bwB[7]=cB7;
            __hip_atomic_store(&prog[w], sb + 7, __ATOMIC_RELEASE,
                               __HIP_MEMORY_SCOPE_WORKGROUP);
        }

        // ---- prefetch group m+1 (y first — no sync dependency; then h) ----
        if (m + 1 < NG) {
            const float* ynA = ybA + 8 * (m + 1);
            const float* ynB = ybB + 8 * (m + 1);
            float a0=ynA[0],a1=ynA[1],a2=ynA[2],a3=ynA[3];
            float a4=ynA[4],a5=ynA[5],a6=ynA[6],a7=ynA[7];
            float e0=ynB[0],e1=ynB[1],e2=ynB[2],e3=ynB[3];
            float e4=ynB[4],e5=ynB[5],e6=ynB[6],e7=ynB[7];
            if (cons) {
                POLL(sb + 15);
                hA0=bbA[sb+8];  hA1=bbA[sb+9];  hA2=bbA[sb+10]; hA3=bbA[sb+11];
                hA4=bbA[sb+12]; hA5=bbA[sb+13]; hA6=bbA[sb+14]; hA7=bbA[sb+15];
                hB0=bbB[sb+8];  hB1=bbB[sb+9];  hB2=bbB[sb+10]; hB3=bbB[sb+11];
                hB4=bbB[sb+12]; hB5=bbB[sb+13]; hB6=bbB[sb+14]; hB7=bbB[sb+15];
            }
            float d;
            d=xvA-a0; qA0=d*CSCL*d;  d=xvA-a1; qA1=d*CSCL*d;
            d=xvA-a2; qA2=d*CSCL*d;  d=xvA-a3; qA3=d*CSCL*d;
            d=xvA-a4; qA4=d*CSCL*d;  d=xvA-a5; qA5=d*CSCL*d;
            d=xvA-a6; qA6=d*CSCL*d;  d=xvA-a7; qA7=d*CSCL*d;
            d=xvB-e0; qB0=d*CSCL*d;  d=xvB-e1; qB1=d*CSCL*d;
            d=xvB-e2; qB2=d*CSCL*d;  d=xvB-e3; qB3=d*CSCL*d;
            d=xvB-e4; qB4=d*CSCL*d;  d=xvB-e5; qB5=d*CSCL*d;
            d=xvB-e6; qB6=d*CSCL*d;  d=xvB-e7; qB7=d*CSCL*d;
        }
    }
    #undef STEPJ2
    #undef POLL
}

// Deterministic 256 -> 1 reduction (shuffle within wave64, LDS across 4 waves)
__global__ __launch_bounds__(256)
void reduce256(const float* __restrict__ ws, float* __restrict__ out) {
    const int tid = threadIdx.x;
    float v = ws[tid];
    #pragma unroll
    for (int off = 32; off > 0; off >>= 1)
        v += __shfl_down(v, off, 64);
    __shared__ float partial[4];
    if ((tid & 63) == 0) partial[tid >> 6] = v;
    __syncthreads();
    if (tid == 0) out[0] = (partial[0] + partial[1]) + (partial[2] + partial[3]);
}

extern "C" void kernel_launch(void* const* d_in, const int* in_sizes, int n_in,
                              void* d_out, int out_size, void* d_ws, size_t ws_size,
                              hipStream_t stream) {
    const float* x = (const float*)d_in[0];
    const float* y = (const float*)d_in[1];
    float* out = (float*)d_out;
    float* ws  = (float*)d_ws;

    const int T = in_sizes[0] / NCH;            // 2048 frames
    const int L = (T + STEP - 1) / STEP;        // 205 subsampled frames

    softdtw_wave<<<dim3(NCH / 2), dim3(256), 0, stream>>>(x, y, ws, L);
    reduce256<<<dim3(1), dim3(256), 0, stream>>>(ws, out);
}

// Round 9
// 48.255 us; speedup vs baseline: 1.1133x; 1.1133x over previous
//
#include <hip/hip_runtime.h>

#define STEP 10
#define NCH  256                 // 128*2 flattened channels = DP "batches"
#define CSCL (-144.2695041f)     // -(1/GAMMA)*log2(e): scale into log2 domain
#define GLN2 (-0.00693147181f)   // -GAMMA*ln(2) == 1/CSCL (to 7e-10 rel)
#define BIGP (-1.442695041e12f)  // 1e10 * CSCL : boundary "BIG" in scaled domain
#define YOFF 64                  // pad: y idx = s-64w-l-2 >= -63
#define YLDS 384                 // YOFF + N + 80 for N <= 240
#define BNDSZ 472                // absolute-diag-indexed boundary ring (no reuse)
#define NW   4                   // waves per batch

// exp2/log2 via raw ISA (no fast-math dependence)
__device__ __forceinline__ float fexp2(float x){ float r; asm("v_exp_f32 %0, %1" : "=v"(r) : "v"(x)); return r; }
__device__ __forceinline__ float flog2(float x){ float r; asm("v_log_f32 %0, %1" : "=v"(r) : "v"(x)); return r; }

// Fused whole-wave shift + lane-0 boundary inject (validated R8, absmax 0.0):
// lane i <- lane i-1's src, lane 0 <- old.
__device__ __forceinline__ float dpp_shr1_sel(float h, float src){
    int o = __builtin_bit_cast(int, h);
    int s = __builtin_bit_cast(int, src);
    int r = __builtin_amdgcn_update_dpp(o, s, 0x138 /*wave_shr:1*/, 0xF, 0xF, false);
    return __builtin_bit_cast(float, r);
}

// Soft-DTW cell, scaled domain R' = R*CSCL, qq precomputed off-chain.
// No boundary mask: invalid cells self-perpetuate at ~BIGP and contribute
// exactly 0.0f through exp2 in any valid cell (validated R4-R8, absmax 0.0).
__device__ __forceinline__ float dpcell(float up2, float up, float left, float qq) {
    float m  = fmaxf(fmaxf(up2, up), left);            // v_max3_f32
    float lo = fminf(fminf(up2, up), left);            // v_min3_f32
    float md = __builtin_amdgcn_fmed3f(up2, up, left); // v_med3_f32
    float e  = fexp2(lo - m) + fexp2(md - m) + 1.0f;
    float mq = m + qq;                                 // off-chain
    return flog2(e) + mq;
}

// Force the 8 values to be materialized in VGPRs HERE. Placed one group after
// the loads were issued, the implicit waitcnt is instant (LDS returns are
// in-order), and LLVM can no longer sink/remat the loads onto the DP chain.
#define PIN8(A0,A1,A2,A3,A4,A5,A6,A7) \
    asm volatile("" : "+v"(A0),"+v"(A1),"+v"(A2),"+v"(A3), \
                      "+v"(A4),"+v"(A5),"+v"(A6),"+v"(A7))

// R7's barrier-free 4-wave lag pipeline (1 row/lane, trimmed spans,
// launch_bounds(256,1)), with:
//  - distance-2 double-buffered prefetch: group m's bottom loads group m+2
//    (POLL first, so the acquire never fences fresh loads); buffers pinned one
//    group after issue -> zero exposed LDS latency anywhere.
//  - deferred release: group m's prog release happens at group m+1 (before its
//    data writes), so the release's lgkmcnt(0) only covers long-done ops.
//  - fused final reduction: last-finished block reduces ws[0..255] (same tree
//    as the old reduce256 -> bitwise-identical output), no second launch.
__global__ __launch_bounds__(256, 1)
void softdtw_wave(const float* __restrict__ x, const float* __restrict__ y,
                  float* __restrict__ ws, int* __restrict__ cnt,
                  float* __restrict__ out, int N) {
    const int b = blockIdx.x;
    const int t = threadIdx.x;          // 0..255
    const int l = t & 63;               // lane within wave
    const int w = t >> 6;               // wave 0..3

    __shared__ __align__(16) float Ys[YLDS];
    __shared__ float bnd[NW - 1][BNDSZ];
    __shared__ int prog[NW - 1];
    __shared__ float res_s;
    __shared__ int last_s;

    for (int j = t; j < YLDS; j += 256) Ys[j] = 0.f;
    float* bf = &bnd[0][0];
    for (int j = t; j < (NW - 1) * BNDSZ; j += 256) bf[j] = BIGP;
    if (t < NW - 1) prog[t] = 0;
    __syncthreads();
    for (int j = t; j < N; j += 256) Ys[YOFF + j] = y[j * STEP * NCH + b];
    __syncthreads();                    // startup-only block barriers

    const int i = 64 * w + l + 1;       // my row
    const float xv = (i <= N) ? x[(i - 1) * STEP * NCH + b] : 0.f;

    // scaled DP state entering diag s:
    //   sp = R'(i, s-1-i)   bp = R'(i-1, s-i)   bq = R'(i-1, s-1-i)
    float sp = BIGP, bp = BIGP;
    float bq = (t == 0) ? 0.0f : BIGP;  // R'[0][0] seed enters at s=2

    const int smax = 2 * N;
    const int sb0  = 64 * w + 2;        // first diagonal of this wave
    const int myrows = (64 * (w + 1) < N) ? 64 * (w + 1) : N;
    const int NG     = (myrows + N - sb0 + 1 + 7) >> 3;   // trimmed groups
    const bool prod = (w < NW - 1);
    const bool cons = (w > 0);
    const int prows = (64 * w < N) ? 64 * w : N;
    const int pNG   = (prows + N - (sb0 - 64) + 1 + 7) >> 3;
    const int progFinal = (sb0 - 64) + 8 * pNG - 1;       // producer's last diag

    const float* yrow = Ys + (YOFF - l);   // group m step J: yrow[8m + J]
    const float* bb = cons ? bnd[w - 1] : bnd[0];

    #define POLL(NEED) do {                                               \
        const int need_ = min((NEED), progFinal);                         \
        while (__hip_atomic_load(&prog[w - 1], __ATOMIC_ACQUIRE,          \
                                 __HIP_MEMORY_SCOPE_WORKGROUP) < need_)   \
            __builtin_amdgcn_s_sleep(1);                                  \
    } while (0)

    // ---- prologue: load groups 0 (buf A) and 1 (buf B); pin A ----
    float ya0,ya1,ya2,ya3,ya4,ya5,ya6,ya7, hb0,hb1,hb2,hb3,hb4,hb5,hb6,hb7;
    float yB0,yB1,yB2,yB3,yB4,yB5,yB6,yB7, ha0,ha1,ha2,ha3,ha4,ha5,ha6,ha7;
    ya0=yrow[0]; ya1=yrow[1]; ya2=yrow[2]; ya3=yrow[3];
    ya4=yrow[4]; ya5=yrow[5]; ya6=yrow[6]; ya7=yrow[7];
    yB0=yrow[8]; yB1=yrow[9]; yB2=yrow[10]; yB3=yrow[11];
    yB4=yrow[12]; yB5=yrow[13]; yB6=yrow[14]; yB7=yrow[15];
    if (cons) {
        POLL(sb0 + 15);
        if (l == 0) bp = bb[sb0 - 1];   // seed R'(64w, 1)
        ha0=bb[sb0+0]; ha1=bb[sb0+1]; ha2=bb[sb0+2]; ha3=bb[sb0+3];
        ha4=bb[sb0+4]; ha5=bb[sb0+5]; ha6=bb[sb0+6]; ha7=bb[sb0+7];
        hb0=bb[sb0+8]; hb1=bb[sb0+9]; hb2=bb[sb0+10]; hb3=bb[sb0+11];
        hb4=bb[sb0+12]; hb5=bb[sb0+13]; hb6=bb[sb0+14]; hb7=bb[sb0+15];
    } else {
        ha0=ha1=ha2=ha3=ha4=ha5=ha6=ha7 = BIGP;   // row-0 wall
        hb0=hb1=hb2=hb3=hb4=hb5=hb6=hb7 = BIGP;
    }
    PIN8(ya0,ya1,ya2,ya3,ya4,ya5,ya6,ya7);
    PIN8(ha0,ha1,ha2,ha3,ha4,ha5,ha6,ha7);

    #define STEPJ(YV, HJ, CJ, J) do {                              \
        float d_ = xv - (YV);                                      \
        float q_ = d_ * CSCL * d_;                                 \
        CJ = dpcell(bq, bp, sp, q_);                               \
        float n_ = dpp_shr1_sel((HJ), CJ);                         \
        bq = bp; bp = n_; sp = CJ;                                 \
        if (sb + (J) == smax && i == N) res_s = CJ * GLN2;         \
    } while (0)

    int m = 0;
    for (; m + 1 < NG; m += 2) {
        {   // ---- group m (buf A) ----
            const int sb = sb0 + 8 * m;
            float c0,c1,c2,c3,c4,c5,c6,c7;
            STEPJ(ya0,ha0,c0,0); STEPJ(ya1,ha1,c1,1);
            STEPJ(ya2,ha2,c2,2); STEPJ(ya3,ha3,c3,3);
            STEPJ(ya4,ha4,c4,4); STEPJ(ya5,ha5,c5,5);
            STEPJ(ya6,ha6,c6,6); STEPJ(ya7,ha7,c7,7);
            if (prod && l == 63) {
                __hip_atomic_store(&prog[w], sb - 1, __ATOMIC_RELEASE,
                                   __HIP_MEMORY_SCOPE_WORKGROUP);   // prev group
                float* bw = &bnd[w][sb];
                bw[0]=c0; bw[1]=c1; bw[2]=c2; bw[3]=c3;
                bw[4]=c4; bw[5]=c5; bw[6]=c6; bw[7]=c7;
            }
            if (m + 2 < NG) {           // prefetch group m+2 into A
                if (cons) {
                    POLL(sb0 + 8*(m+2) + 7);
                    const float* hh = &bb[sb0 + 8*(m+2)];
                    ha0=hh[0]; ha1=hh[1]; ha2=hh[2]; ha3=hh[3];
                    ha4=hh[4]; ha5=hh[5]; ha6=hh[6]; ha7=hh[7];
                }
                const float* yn = yrow + 8*(m+2);
                ya0=yn[0]; ya1=yn[1]; ya2=yn[2]; ya3=yn[3];
                ya4=yn[4]; ya5=yn[5]; ya6=yn[6]; ya7=yn[7];
            }
            PIN8(yB0,yB1,yB2,yB3,yB4,yB5,yB6,yB7);   // B: loaded last body
            PIN8(hb0,hb1,hb2,hb3,hb4,hb5,hb6,hb7);
        }
        {   // ---- group m+1 (buf B) ----
            const int sb = sb0 + 8 * (m + 1);
            float c0,c1,c2,c3,c4,c5,c6,c7;
            STEPJ(yB0,hb0,c0,0); STEPJ(yB1,hb1,c1,1);
            STEPJ(yB2,hb2,c2,2); STEPJ(yB3,hb3,c3,3);
            STEPJ(yB4,hb4,c4,4); STEPJ(yB5,hb5,c5,5);
            STEPJ(yB6,hb6,c6,6); STEPJ(yB7,hb7,c7,7);
            if (prod && l == 63) {
                __hip_atomic_store(&prog[w], sb - 1, __ATOMIC_RELEASE,
                                   __HIP_MEMORY_SCOPE_WORKGROUP);
                float* bw = &bnd[w][sb];
                bw[0]=c0; bw[1]=c1; bw[2]=c2; bw[3]=c3;
                bw[4]=c4; bw[5]=c5; bw[6]=c6; bw[7]=c7;
            }
            if (m + 3 < NG) {           // prefetch group m+3 into B
                if (cons) {
                    POLL(sb0 + 8*(m+3) + 7);
                    const float* hh = &bb[sb0 + 8*(m+3)];
                    hb0=hh[0]; hb1=hh[1]; hb2=hh[2]; hb3=hh[3];
                    hb4=hh[4]; hb5=hh[5]; hb6=hh[6]; hb7=hh[7];
                }
                const float* yn = yrow + 8*(m+3);
                yB0=yn[0]; yB1=yn[1]; yB2=yn[2]; yB3=yn[3];
                yB4=yn[4]; yB5=yn[5]; yB6=yn[6]; yB7=yn[7];
            }
            PIN8(ya0,ya1,ya2,ya3,ya4,ya5,ya6,ya7);
            PIN8(ha0,ha1,ha2,ha3,ha4,ha5,ha6,ha7);
        }
    }
    if (m < NG) {   // odd tail group (buf A)
        const int sb = sb0 + 8 * m;
        float c0,c1,c2,c3,c4,c5,c6,c7;
        STEPJ(ya0,ha0,c0,0); STEPJ(ya1,ha1,c1,1);
        STEPJ(ya2,ha2,c2,2); STEPJ(ya3,ha3,c3,3);
        STEPJ(ya4,ha4,c4,4); STEPJ(ya5,ha5,c5,5);
        STEPJ(ya6,ha6,c6,6); STEPJ(ya7,ha7,c7,7);
        if (prod && l == 63) {
            __hip_atomic_store(&prog[w], sb - 1, __ATOMIC_RELEASE,
                               __HIP_MEMORY_SCOPE_WORKGROUP);
            float* bw = &bnd[w][sb];
            bw[0]=c0; bw[1]=c1; bw[2]=c2; bw[3]=c3;
            bw[4]=c4; bw[5]=c5; bw[6]=c6; bw[7]=c7;
        }
    }
    if (prod && l == 63)                // final release: everything published
        __hip_atomic_store(&prog[w], 0x3FFFFFFF, __ATOMIC_RELEASE,
                           __HIP_MEMORY_SCOPE_WORKGROUP);
    #undef STEPJ
    #undef POLL

    // ---- fused 256 -> 1 reduction: last finished block reduces ws ----
    __syncthreads();                    // res_s written (by the i==N lane)
    if (t == 0) {
        __hip_atomic_store(&ws[b], res_s, __ATOMIC_RELEASE,
                           __HIP_MEMORY_SCOPE_AGENT);
        int prev = __hip_atomic_fetch_add(cnt, 1, __ATOMIC_ACQ_REL,
                                          __HIP_MEMORY_SCOPE_AGENT);
        last_s = (prev == NCH - 1);
    }
    __syncthreads();
    if (last_s) {                       // exactly one block runs this
        float v = __hip_atomic_load(&ws[t], __ATOMIC_RELAXED,
                                    __HIP_MEMORY_SCOPE_AGENT);
        #pragma unroll
        for (int off = 32; off > 0; off >>= 1)
            v += __shfl_down(v, off, 64);
        __shared__ float partial[4];
        if ((t & 63) == 0) partial[t >> 6] = v;
        __syncthreads();
        if (t == 0) out[0] = (partial[0] + partial[1]) + (partial[2] + partial[3]);
    }
}

extern "C" void kernel_launch(void* const* d_in, const int* in_sizes, int n_in,
                              void* d_out, int out_size, void* d_ws, size_t ws_size,
                              hipStream_t stream) {
    const float* x = (const float*)d_in[0];
    const float* y = (const float*)d_in[1];
    float* out = (float*)d_out;
    float* ws  = (float*)d_ws;
    int*   cnt = (int*)(ws + NCH);

    const int T = in_sizes[0] / NCH;            // 2048 frames
    const int L = (T + STEP - 1) / STEP;        // 205 subsampled frames

    hipMemsetAsync(cnt, 0, sizeof(int), stream);
    softdtw_wave<<<dim3(NCH), dim3(256), 0, stream>>>(x, y, ws, cnt, out, L);
}